// Round 2
// baseline (856.832 us; speedup 1.0000x reference)
//
#include <hip/hip_runtime.h>

#define L_DIM 4096
#define H_DIM 16
#define E_DIM 64
#define BH 128
#define ROWSTRIDE 1024  // H_DIM*E_DIM floats between consecutive l
#define STG 32          // rows staged per barrier

__device__ __forceinline__ float inv_softplus_temp(const float* delta1) {
  return 1.0f / log1pf(__expf(delta1[0]));
}

__device__ __forceinline__ float4 exp_clamp4(float4 x, float it) {
  float4 r;
  r.x = __expf((x.x < 0.f ? -20.f : x.x) * it);
  r.y = __expf((x.y < 0.f ? -20.f : x.y) * it);
  r.z = __expf((x.z < 0.f ? -20.f : x.z) * it);
  r.w = __expf((x.w < 0.f ? -20.f : x.w) * it);
  return r;
}

// Phase 1: per (b,h,chunk) partial KV[d][e] = sum_l ktil[l][d]*v[l][e], ksum[d].
// 8x8 per-thread tiles, rows split across waves, dbuf LDS w/ 1 barrier/stage,
// register prefetch of next stage's global loads. No atomics.
__global__ __launch_bounds__(256, 4) void p1_kv(
    const float* __restrict__ Kp, const float* __restrict__ Vp,
    const float* __restrict__ delta1,
    float* __restrict__ part_kv, float* __restrict__ part_ks) {
  const int t = threadIdx.x;
  const int bh = blockIdx.y;
  const int b = bh >> 4, h = bh & 15;
  const int lane = t & 63;
  const int w = t >> 6;
  const float inv_temp = inv_softplus_temp(delta1);
  const size_t base = ((size_t)b * L_DIM * H_DIM + h) * E_DIM;
  const int chunk = L_DIM / gridDim.x;
  const int nstage = chunk / STG;
  const int l0 = blockIdx.x * chunk;

  __shared__ float sk[2][STG][64];
  __shared__ float sv[2][STG][64];

  const int srow = t >> 4;          // 0..15 staging row slot
  const int equad = (t & 15) << 2;  // staging column quad
  const int d0 = (lane >> 3) << 3;  // 8x8 tile: d in [d0,d0+8)
  const int e0 = (lane & 7) << 3;   //          e in [e0,e0+8)

  float acc[8][8];
#pragma unroll
  for (int i = 0; i < 8; ++i)
#pragma unroll
    for (int j = 0; j < 8; ++j) acc[i][j] = 0.f;
  float4 ksacc = make_float4(0.f, 0.f, 0.f, 0.f);

  const float* kbase = Kp + base + equad;
  const float* vbase = Vp + base + equad;

  float4 ck0, ck1, cv0, cv1;
  {
    const size_t r = (size_t)(l0 + srow) * ROWSTRIDE;
    ck0 = *(const float4*)(kbase + r);
    ck1 = *(const float4*)(kbase + r + 16 * (size_t)ROWSTRIDE);
    cv0 = *(const float4*)(vbase + r);
    cv1 = *(const float4*)(vbase + r + 16 * (size_t)ROWSTRIDE);
  }

  for (int s = 0; s < nstage; ++s) {
    const int buf = s & 1;
    // softmax-normalize the two staged k rows (rows srow, srow+16)
    float4 E0 = exp_clamp4(ck0, inv_temp);
    float4 E1 = exp_clamp4(ck1, inv_temp);
    float s0 = E0.x + E0.y + E0.z + E0.w;
    float s1 = E1.x + E1.y + E1.z + E1.w;
    s0 += __shfl_xor(s0, 1); s1 += __shfl_xor(s1, 1);
    s0 += __shfl_xor(s0, 2); s1 += __shfl_xor(s1, 2);
    s0 += __shfl_xor(s0, 4); s1 += __shfl_xor(s1, 4);
    s0 += __shfl_xor(s0, 8); s1 += __shfl_xor(s1, 8);
    const float r0 = __builtin_amdgcn_rcpf(s0);
    const float r1 = __builtin_amdgcn_rcpf(s1);
    const float4 kt0 = make_float4(E0.x * r0, E0.y * r0, E0.z * r0, E0.w * r0);
    const float4 kt1 = make_float4(E1.x * r1, E1.y * r1, E1.z * r1, E1.w * r1);
    ksacc.x += kt0.x + kt1.x;
    ksacc.y += kt0.y + kt1.y;
    ksacc.z += kt0.z + kt1.z;
    ksacc.w += kt0.w + kt1.w;
    *(float4*)&sk[buf][srow][equad] = kt0;
    *(float4*)&sk[buf][srow + 16][equad] = kt1;
    *(float4*)&sv[buf][srow][equad] = cv0;
    *(float4*)&sv[buf][srow + 16][equad] = cv1;
    __syncthreads();  // single barrier per stage (dbuf covers WAR)
    if (s + 1 < nstage) {  // prefetch next stage; latency hidden by FMA below
      const size_t r = (size_t)(l0 + (s + 1) * STG + srow) * ROWSTRIDE;
      ck0 = *(const float4*)(kbase + r);
      ck1 = *(const float4*)(kbase + r + 16 * (size_t)ROWSTRIDE);
      cv0 = *(const float4*)(vbase + r);
      cv1 = *(const float4*)(vbase + r + 16 * (size_t)ROWSTRIDE);
    }
    // wave w consumes rows [w*8, w*8+8): each row read by exactly one wave
#pragma unroll
    for (int rr = 0; rr < 8; ++rr) {
      const int row = (w << 3) + rr;
      const float4 a0 = *(const float4*)&sk[buf][row][d0];
      const float4 a1 = *(const float4*)&sk[buf][row][d0 + 4];
      const float4 b0 = *(const float4*)&sv[buf][row][e0];
      const float4 b1 = *(const float4*)&sv[buf][row][e0 + 4];
      const float ka[8] = {a0.x, a0.y, a0.z, a0.w, a1.x, a1.y, a1.z, a1.w};
      const float vb[8] = {b0.x, b0.y, b0.z, b0.w, b1.x, b1.y, b1.z, b1.w};
#pragma unroll
      for (int i = 0; i < 8; ++i)
#pragma unroll
        for (int j = 0; j < 8; ++j)
          acc[i][j] = fmaf(ka[i], vb[j], acc[i][j]);
    }
  }

  __syncthreads();
  // ksum partials -> sv area
  float* redks = &sv[0][0][0];
  *(float4*)&redks[srow * 64 + equad] = ksacc;
  // cross-wave KV reduction in sk area (exactly 4096 floats)
  float* red = &sk[0][0][0];
  for (int ww = 0; ww < 4; ++ww) {
    if (w == ww) {
#pragma unroll
      for (int i = 0; i < 8; ++i) {
        float* dst = &red[(d0 + i) * 64 + e0];
        float4 x0 = make_float4(acc[i][0], acc[i][1], acc[i][2], acc[i][3]);
        float4 x1 = make_float4(acc[i][4], acc[i][5], acc[i][6], acc[i][7]);
        if (ww != 0) {
          const float4 y0 = *(const float4*)&dst[0];
          const float4 y1 = *(const float4*)&dst[4];
          x0.x += y0.x; x0.y += y0.y; x0.z += y0.z; x0.w += y0.w;
          x1.x += y1.x; x1.y += y1.y; x1.z += y1.z; x1.w += y1.w;
        }
        *(float4*)&dst[0] = x0;
        *(float4*)&dst[4] = x1;
      }
    }
    __syncthreads();
  }
  const int pb = blockIdx.y * gridDim.x + blockIdx.x;
  float* dkv = part_kv + (size_t)pb * 4096;
#pragma unroll
  for (int kk = 0; kk < 4; ++kk)
    *(float4*)&dkv[kk * 1024 + t * 4] = *(const float4*)&red[kk * 1024 + t * 4];
  if (t < 64) {
    float sum = 0.f;
#pragma unroll
    for (int r = 0; r < 16; ++r) sum += redks[r * 64 + t];
    part_ks[pb * 64 + t] = sum;
  }
}

// Reduce px partials per (b,h) into final KV + ksum. Tiny (~17 MB read).
__global__ __launch_bounds__(256) void p1_reduce(
    const float* __restrict__ part_kv, const float* __restrict__ part_ks,
    float* __restrict__ kv, float* __restrict__ ksum, int px) {
  const int bh = blockIdx.x;
  const int t = threadIdx.x;
#pragma unroll 4
  for (int i = 0; i < 16; ++i) {
    const int j = i * 256 + t;
    float s = 0.f;
    for (int p = 0; p < px; ++p)
      s += part_kv[(size_t)(bh * px + p) * 4096 + j];
    kv[(size_t)bh * 4096 + j] = s;
  }
  if (t < 64) {
    float s = 0.f;
    for (int p = 0; p < px; ++p)
      s += part_ks[(bh * px + p) * 64 + t];
    ksum[bh * 64 + t] = s;
  }
}

// Phase 2: out[l][d] = sum_e w[l][e]*KV[e][d], w = Eq/(Eq.ksum + eps*sum(Eq)).
// KV column d=lane in 64 regs; weights via LDS [row][e] (conflict-free writes,
// broadcast reads); dbuf + 1 barrier/stage + register prefetch.
__global__ __launch_bounds__(256, 4) void p2_out(
    const float* __restrict__ Qp, const float* __restrict__ delta1,
    const float* __restrict__ kv, const float* __restrict__ ksum,
    float* __restrict__ outp) {
  const int t = threadIdx.x;
  const int bh = blockIdx.y;
  const int b = bh >> 4, h = bh & 15;
  const int lane = t & 63;
  const int w = t >> 6;
  const float inv_temp = inv_softplus_temp(delta1);
  const size_t base = ((size_t)b * L_DIM * H_DIM + h) * E_DIM;
  const int chunk = L_DIM / gridDim.x;  // 512
  const int nstage = chunk / STG;       // 16
  const int l0 = blockIdx.x * chunk;

  __shared__ float sw[2][STG][64];  // [buf][row][e]: write banks=e -> 2-way=free

  const int srow = t >> 4;
  const int equad = (t & 15) << 2;

  float kvcol[64];
#pragma unroll
  for (int e = 0; e < 64; ++e)
    kvcol[e] = kv[(size_t)bh * 4096 + e * 64 + lane];
  const float4 ks4 = *(const float4*)&ksum[bh * 64 + equad];

  const float* qbase = Qp + base + equad;
  float* obase = outp + base;

  float4 cq0, cq1;
  {
    const size_t r = (size_t)(l0 + srow) * ROWSTRIDE;
    cq0 = *(const float4*)(qbase + r);
    cq1 = *(const float4*)(qbase + r + 16 * (size_t)ROWSTRIDE);
  }

  for (int s = 0; s < nstage; ++s) {
    const int buf = s & 1;
    float4 E0 = exp_clamp4(cq0, inv_temp);
    float4 E1 = exp_clamp4(cq1, inv_temp);
    float sE0 = E0.x + E0.y + E0.z + E0.w;
    float sE1 = E1.x + E1.y + E1.z + E1.w;
    float sD0 = E0.x * ks4.x + E0.y * ks4.y + E0.z * ks4.z + E0.w * ks4.w;
    float sD1 = E1.x * ks4.x + E1.y * ks4.y + E1.z * ks4.z + E1.w * ks4.w;
    sE0 += __shfl_xor(sE0, 1); sD0 += __shfl_xor(sD0, 1);
    sE1 += __shfl_xor(sE1, 1); sD1 += __shfl_xor(sD1, 1);
    sE0 += __shfl_xor(sE0, 2); sD0 += __shfl_xor(sD0, 2);
    sE1 += __shfl_xor(sE1, 2); sD1 += __shfl_xor(sD1, 2);
    sE0 += __shfl_xor(sE0, 4); sD0 += __shfl_xor(sD0, 4);
    sE1 += __shfl_xor(sE1, 4); sD1 += __shfl_xor(sD1, 4);
    sE0 += __shfl_xor(sE0, 8); sD0 += __shfl_xor(sD0, 8);
    sE1 += __shfl_xor(sE1, 8); sD1 += __shfl_xor(sD1, 8);
    // scale = z/sE: out row = (E . KV) / (sD + eps*sE) -- exact eps semantics
    const float sc0 = __builtin_amdgcn_rcpf(sD0 + 1e-6f * sE0);
    const float sc1 = __builtin_amdgcn_rcpf(sD1 + 1e-6f * sE1);
    *(float4*)&sw[buf][srow][equad] =
        make_float4(E0.x * sc0, E0.y * sc0, E0.z * sc0, E0.w * sc0);
    *(float4*)&sw[buf][srow + 16][equad] =
        make_float4(E1.x * sc1, E1.y * sc1, E1.z * sc1, E1.w * sc1);
    __syncthreads();
    if (s + 1 < nstage) {
      const size_t r = (size_t)(l0 + (s + 1) * STG + srow) * ROWSTRIDE;
      cq0 = *(const float4*)(qbase + r);
      cq1 = *(const float4*)(qbase + r + 16 * (size_t)ROWSTRIDE);
    }
    float a[8];
#pragma unroll
    for (int r8 = 0; r8 < 8; ++r8) a[r8] = 0.f;
    const int rb = w << 2;  // wave w owns stage-rows rb..rb+3 and rb+16..rb+19
#pragma unroll
    for (int e = 0; e < 64; ++e) {
      const float kve = kvcol[e];
      a[0] = fmaf(sw[buf][rb + 0][e], kve, a[0]);
      a[1] = fmaf(sw[buf][rb + 1][e], kve, a[1]);
      a[2] = fmaf(sw[buf][rb + 2][e], kve, a[2]);
      a[3] = fmaf(sw[buf][rb + 3][e], kve, a[3]);
      a[4] = fmaf(sw[buf][rb + 16][e], kve, a[4]);
      a[5] = fmaf(sw[buf][rb + 17][e], kve, a[5]);
      a[6] = fmaf(sw[buf][rb + 18][e], kve, a[6]);
      a[7] = fmaf(sw[buf][rb + 19][e], kve, a[7]);
    }
    const size_t lrow = (size_t)(l0 + s * STG + rb) * ROWSTRIDE + lane;
    obase[lrow] = a[0];
    obase[lrow + ROWSTRIDE] = a[1];
    obase[lrow + 2 * (size_t)ROWSTRIDE] = a[2];
    obase[lrow + 3 * (size_t)ROWSTRIDE] = a[3];
    obase[lrow + 16 * (size_t)ROWSTRIDE] = a[4];
    obase[lrow + 17 * (size_t)ROWSTRIDE] = a[5];
    obase[lrow + 18 * (size_t)ROWSTRIDE] = a[6];
    obase[lrow + 19 * (size_t)ROWSTRIDE] = a[7];
  }
}

extern "C" void kernel_launch(void* const* d_in, const int* in_sizes, int n_in,
                              void* d_out, int out_size, void* d_ws, size_t ws_size,
                              hipStream_t stream) {
  (void)in_sizes; (void)n_in; (void)out_size;
  const float* Q = (const float*)d_in[0];
  const float* K = (const float*)d_in[1];
  const float* V = (const float*)d_in[2];
  const float* delta1 = (const float*)d_in[3];
  float* out = (float*)d_out;

  // pick partials-per-bh that fits the workspace
  int px = 8;
  for (;;) {
    size_t need = ((size_t)BH * px * 4096 + (size_t)BH * px * 64 +
                   (size_t)BH * 4096 + (size_t)BH * 64) * sizeof(float);
    if (need <= ws_size || px == 1) break;
    px >>= 1;
  }
  float* part_kv = (float*)d_ws;
  float* part_ks = part_kv + (size_t)BH * px * 4096;
  float* kvf = part_ks + (size_t)BH * px * 64;
  float* ksf = kvf + (size_t)BH * 4096;

  p1_kv<<<dim3(px, BH), 256, 0, stream>>>(K, V, delta1, part_kv, part_ks);
  p1_reduce<<<dim3(BH), 256, 0, stream>>>(part_kv, part_ks, kvf, ksf, px);
  p2_out<<<dim3(8, BH), 256, 0, stream>>>(Q, delta1, kvf, ksf, out);
}